// Round 1
// baseline (4507.515 us; speedup 1.0000x reference)
//
#include <hip/hip_runtime.h>
#include <stdint.h>

typedef unsigned short u16;
typedef __bf16 bf16_t;
typedef bf16_t bf16x8 __attribute__((ext_vector_type(8)));
typedef float f32x4 __attribute__((ext_vector_type(4)));

#define Bdim 64
#define Tdim 256
#define Ddim 512
#define Hdim 1024
#define NGdim 4096

// ---------- helpers ----------
__device__ __forceinline__ u16 f2bf(float f) {
  union { float f; uint32_t u; } v; v.f = f;
  return (u16)((v.u + 0x7FFFu + ((v.u >> 16) & 1u)) >> 16);   // RNE
}
__device__ __forceinline__ float bf2f(u16 h) {
  union { uint32_t u; float f; } v; v.u = ((uint32_t)h) << 16;
  return v.f;
}
__device__ __forceinline__ float sigm(float x) { return 1.0f / (1.0f + __expf(-x)); }
__device__ __forceinline__ float tanh_fast(float x) { return 2.0f / (1.0f + __expf(-2.0f * x)) - 1.0f; }

__device__ __forceinline__ void load_lds16(const void* g, void* l) {
  __builtin_amdgcn_global_load_lds(
      (const __attribute__((address_space(1))) uint32_t*)g,
      (__attribute__((address_space(3))) uint32_t*)l, 16, 0, 0);
}
__device__ __forceinline__ f32x4 mfma_bf16(bf16x8 a, bf16x8 b, f32x4 c) {
  return __builtin_amdgcn_mfma_f32_16x16x32_bf16(a, b, c, 0, 0, 0);
}

// ---------- kernel 0: zero h double-buffer (bf16) + flags region ----------
__global__ void k_init(uint64_t* __restrict__ zreg) {
  zreg[blockIdx.x * 256 + threadIdx.x] = 0ull;   // 256 WGs x 256 x 8 B = 512 KB
}

// ---------- kernel 1: x fp32 -> bf16 ----------
__global__ void k_convert_x(const float* __restrict__ x, u16* __restrict__ xb) {
  const int i = (blockIdx.x * 256 + threadIdx.x) * 4;
  float4 v = *(const float4*)(x + i);
  union { u16 h[4]; uint2 v2; } p;
  p.h[0] = f2bf(v.x); p.h[1] = f2bf(v.y); p.h[2] = f2bf(v.z); p.h[3] = f2bf(v.w);
  *(uint2*)(xb + i) = p.v2;
}

// ---------- kernel 2: W[0:512][4096] fp32 -> WxT bf16 [4096][512] ----------
__global__ void k_transpose_wx(const float* __restrict__ W, u16* __restrict__ wxt) {
  __shared__ float tile[64][65];
  const int k0 = blockIdx.x * 64;   // 8 blocks
  const int n0 = blockIdx.y * 64;   // 64 blocks
  const int tn = threadIdx.x & 63, tk = threadIdx.x >> 6;
#pragma unroll
  for (int r = 0; r < 16; r++) {
    const int k = r * 4 + tk;
    tile[k][tn] = W[(size_t)(k0 + k) * NGdim + n0 + tn];
  }
  __syncthreads();
  for (int cid = threadIdx.x; cid < 512; cid += 256) {
    const int nl = cid >> 3, kc = cid & 7;
    union { u16 h[8]; uint4 v; } p;
#pragma unroll
    for (int j = 0; j < 8; j++) p.h[j] = f2bf(tile[kc * 8 + j][nl]);
    *(uint4*)(wxt + (size_t)(n0 + nl) * Ddim + k0 + kc * 8) = p.v;
  }
}

// ---------- kernel 3: W_h -> per-WG fragment layout whT[gid][128 kb][16 n][8 kk] bf16 (8 MB) ----------
__global__ void k_prep_wh(const float* __restrict__ W, u16* __restrict__ whT) {
  const int gid = blockIdx.x;          // 0..255
  u16* dst = whT + (size_t)gid * 16384;
  const int gate = threadIdx.x & 3;
  const int kb = threadIdx.x >> 2;     // 0..63
  const int ngc = gate * 1024 + gid * 4;
#pragma unroll 1
  for (int kk = 0; kk < 16; kk++) {
    const int k = kb * 16 + kk;
    const float4 wv = *(const float4*)(W + (size_t)(Ddim + k) * NGdim + ngc);
    const int base = ((k >> 3) * 16 + gate * 4) * 8 + (k & 7);
    dst[base]      = f2bf(wv.x);
    dst[base + 8]  = f2bf(wv.y);
    dst[base + 16] = f2bf(wv.z);
    dst[base + 24] = f2bf(wv.w);
  }
}

// ---------- kernel 4: XW = x @ Wx + b, permuted output [T][256 g][64 b][16 nl] bf16 ----------
__global__ __launch_bounds__(256) void k_gemm_xw(
    const u16* __restrict__ xb, const u16* __restrict__ wxt,
    const float* __restrict__ bias, u16* __restrict__ xw)
{
  __shared__ u16 smem[8192];        // 16 KB: sA [kg][128 m][8], sB [kg][128 j][8]
  const int Mtile = blockIdx.x;     // 0..127 (2 t's x 64 b)
  const int Ntile = blockIdx.y;     // 0..31
  const int g0 = Ntile * 8;
  const int tid = threadIdx.x;
  const int lane = tid & 63;
  const int wave = tid >> 6;
  const int wm = wave & 1, wn = wave >> 1;
  const int t0 = Mtile * 2;

  const size_t a_r0 = ((size_t)lane * Tdim + t0) * Ddim;
  const size_t a_r1 = ((size_t)lane * Tdim + t0 + 1) * Ddim;
  const int jc0 = lane, jc1 = 64 + lane;
  const int ng0 = (jc0 >> 5) * 1024 + (g0 + ((jc0 >> 2) & 7)) * 4 + (jc0 & 3);
  const int ng1 = (jc1 >> 5) * 1024 + (g0 + ((jc1 >> 2) & 7)) * 4 + (jc1 & 3);
  const size_t b_r0 = (size_t)ng0 * Ddim;
  const size_t b_r1 = (size_t)ng1 * Ddim;

  u16* sA = smem;
  u16* sB = smem + 4096;
  char* dA0 = (char*)sA + wave * 2048;
  char* dA1 = dA0 + 1024;
  char* dB0 = (char*)sB + wave * 2048;
  char* dB1 = dB0 + 1024;

  f32x4 zero4 = {0.f, 0.f, 0.f, 0.f};
  f32x4 acc[4][4];
#pragma unroll
  for (int i = 0; i < 4; i++)
#pragma unroll
    for (int j = 0; j < 4; j++) acc[i][j] = zero4;

  const int fa = (((lane >> 4) * 128) + wm * 64 + (lane & 15)) * 16;
  const int fb = (((lane >> 4) * 128) + wn * 64 + (lane & 15)) * 16;

  for (int k0 = 0; k0 < Ddim; k0 += 32) {
    const int koff = k0 + 8 * wave;
    __syncthreads();
    load_lds16(xb + a_r0 + koff, dA0);
    load_lds16(xb + a_r1 + koff, dA1);
    load_lds16(wxt + b_r0 + koff, dB0);
    load_lds16(wxt + b_r1 + koff, dB1);
    __syncthreads();
    bf16x8 af[4], bfr[4];
#pragma unroll
    for (int i = 0; i < 4; i++) {
      af[i]  = *(const bf16x8*)((const char*)sA + fa + i * 256);
      bfr[i] = *(const bf16x8*)((const char*)sB + fb + i * 256);
    }
#pragma unroll
    for (int mt = 0; mt < 4; mt++)
#pragma unroll
      for (int nt = 0; nt < 4; nt++)
        acc[mt][nt] = mfma_bf16(af[mt], bfr[nt], acc[mt][nt]);
  }

#pragma unroll 1
  for (int th = 0; th < 2; th++) {
    __syncthreads();
    if (wm == th) {
      const int q = lane >> 4, col0 = wn * 64 + (lane & 15);
#pragma unroll
      for (int mt = 0; mt < 4; mt++)
#pragma unroll
        for (int nt = 0; nt < 4; nt++)
#pragma unroll
          for (int i = 0; i < 4; i++)
            smem[(mt * 16 + q * 4 + i) * 128 + col0 + nt * 16] = f2bf(acc[mt][nt][i]);
    }
    __syncthreads();
    const int t = t0 + th;
    for (int cid = tid; cid < 512; cid += 256) {
      const int gsub = cid >> 6;
      const int b = cid & 63;
      union { u16 h[16]; uint4 v[2]; } pack;
#pragma unroll
      for (int gate = 0; gate < 4; gate++)
#pragma unroll
        for (int c = 0; c < 4; c++) {
          float v = bf2f(smem[b * 128 + gate * 32 + gsub * 4 + c])
                  + bias[gate * 1024 + (g0 + gsub) * 4 + c];
          pack.h[gate * 4 + c] = f2bf(v);
        }
      uint4* dst = (uint4*)(xw + ((((size_t)t * 256) + g0 + gsub) * 64 + b) * 16);
      dst[0] = pack.v[0];
      dst[1] = pack.v[1];
    }
  }
}

// ---------- kernel 5: persistent cooperative LSTM recurrence ----------
// One launch for all 256 timesteps. 256 WGs x 256 threads (1 WG/CU).
// WG gid owns h-cols [gid*4, gid*4+4) x 4 gates (16 z-cols). Wave w holds the
// W_h fragments for K-slice [w*256, w*256+256) permanently in 32 VGPRs; partial
// z-sums are reduced across waves through LDS. Each thread owns one (batch,
// h-col) cell: c and carried h live in registers for the whole sequence.
// Cross-WG step sync: per-WG flag (128 B padded) written with agent-scope
// release store (h slice stored write-through agent-scope first, same wave),
// lane-parallel relaxed polling + agent acquire fence on the consumer side.
__global__ __launch_bounds__(256, 1) void k_lstm_persist(
    const u16* __restrict__ whT, const u16* __restrict__ xw,
    const int* __restrict__ seq_len, u16* __restrict__ hbuf,
    uint32_t* __restrict__ flags, float* __restrict__ out)
{
  __shared__ float zlds[4 * 64 * 17];   // [wave][batch][col], col-pad 17
  __shared__ u16 hpack[64][4];
  const int gid  = blockIdx.x;          // 0..255
  const int tid  = threadIdx.x;
  const int lane = tid & 63;
  const int wave = tid >> 6;
  const int b_t  = tid >> 2;            // owned batch
  const int c_t  = tid & 3;             // owned h-col within gid*4
  const int q    = lane >> 4;
  const int col  = lane & 15;

  // W_h fragments, loaded once: kt = wave*8 + j covers K [wave*256, wave*256+256)
  bf16x8 bw[8];
  {
    const u16* wp = whT + (size_t)gid * 16384 + ((size_t)q * 16 + col) * 8;
#pragma unroll
    for (int j = 0; j < 8; j++)
      bw[j] = *(const bf16x8*)(wp + (wave * 8 + j) * 512);
  }

  const int slen = seq_len[b_t];
  float c_reg = 0.f, h_reg = 0.f;

  for (int t = 0; t < Tdim; t++) {
    const u16* hsrc = hbuf + (size_t)(t & 1) * (Bdim * Hdim);
    u16* hdst = hbuf + (size_t)((t + 1) & 1) * (Bdim * Hdim);

    if (t > 0) {
      if (wave == 0) {
        const uint32_t gen = (uint32_t)t;
        for (;;) {
          const uint32_t f0 = __hip_atomic_load(flags + (size_t)lane * 32,
                                                __ATOMIC_RELAXED, __HIP_MEMORY_SCOPE_AGENT);
          const uint32_t f1 = __hip_atomic_load(flags + (size_t)(lane + 64) * 32,
                                                __ATOMIC_RELAXED, __HIP_MEMORY_SCOPE_AGENT);
          const uint32_t f2 = __hip_atomic_load(flags + (size_t)(lane + 128) * 32,
                                                __ATOMIC_RELAXED, __HIP_MEMORY_SCOPE_AGENT);
          const uint32_t f3 = __hip_atomic_load(flags + (size_t)(lane + 192) * 32,
                                                __ATOMIC_RELAXED, __HIP_MEMORY_SCOPE_AGENT);
          if (__all((f0 >= gen) && (f1 >= gen) && (f2 >= gen) && (f3 >= gen))) break;
          __builtin_amdgcn_s_sleep(1);
        }
      }
      __syncthreads();
      __builtin_amdgcn_fence(__ATOMIC_ACQUIRE, "agent");  // make other WGs' h stores visible
    }

    // precomputed x@Wx + b contribution for this (t, b, cols)
    const u16* xwp = xw + ((((size_t)t * 256) + gid) * 64 + b_t) * 16 + c_t;
    const float xi = bf2f(xwp[0]);
    const float xj = bf2f(xwp[4]);
    const float xf = bf2f(xwp[8]);
    const float xo = bf2f(xwp[12]);

    // h @ Wh partial for this wave's K-slice: all 64 batches x 16 z-cols
    const f32x4 zero4 = {0.f, 0.f, 0.f, 0.f};
    f32x4 acc[4] = {zero4, zero4, zero4, zero4};
    const u16* pa = hsrc + (size_t)col * Hdim + wave * 256 + q * 8;
#pragma unroll
    for (int j = 0; j < 8; j++) {
#pragma unroll
      for (int mt = 0; mt < 4; mt++) {
        const bf16x8 av = *(const bf16x8*)(pa + (size_t)mt * 16 * Hdim + j * 32);
        acc[mt] = mfma_bf16(av, bw[j], acc[mt]);
      }
    }

    // partial z tile -> LDS (C/D layout: col=lane&15, row=(lane>>4)*4+i)
#pragma unroll
    for (int mt = 0; mt < 4; mt++)
#pragma unroll
      for (int i = 0; i < 4; i++)
        zlds[(wave * 64 + mt * 16 + q * 4 + i) * 17 + col] = acc[mt][i];
    __syncthreads();

    // cross-wave K-reduction + gates; thread owns (b_t, gid*4 + c_t)
    float zi = xi, zj = xj, zf = xf, zo = xo;
#pragma unroll
    for (int w = 0; w < 4; w++) {
      const float* zr = zlds + (w * 64 + b_t) * 17 + c_t;
      zi += zr[0]; zj += zr[4]; zf += zr[8]; zo += zr[12];
    }
    if (t < slen) {
      c_reg = c_reg * sigm(zf + 1.0f) + sigm(zi) * tanh_fast(zj);
      h_reg = tanh_fast(c_reg) * sigm(zo);
    }

    if (t == Tdim - 1) break;   // final h stays in h_reg; nobody reads hdst

    // publish this WG's h slice: pack 4 cols/batch -> one 8 B agent store per batch
    hpack[b_t][c_t] = f2bf(h_reg);
    __syncthreads();
    if (wave == 0) {
      const uint64_t pk = *(const uint64_t*)(&hpack[lane][0]);
      __hip_atomic_store((uint64_t*)(hdst + (size_t)lane * Hdim + gid * 4), pk,
                         __ATOMIC_RELAXED, __HIP_MEMORY_SCOPE_AGENT);
      if (lane == 0)
        __hip_atomic_store(flags + (size_t)gid * 32, (uint32_t)(t + 1),
                           __ATOMIC_RELEASE, __HIP_MEMORY_SCOPE_AGENT);
    }
    // no trailing barrier needed: next iteration's first LDS touch is after
    // the t>0 __syncthreads above, which wave 0 reaches only after its stores
  }

  out[(size_t)b_t * Hdim + gid * 4 + c_t] = h_reg;
}

// ---------- host ----------
extern "C" void kernel_launch(void* const* d_in, const int* in_sizes, int n_in,
                              void* d_out, int out_size, void* d_ws, size_t ws_size,
                              hipStream_t stream) {
  (void)in_sizes; (void)n_in; (void)out_size; (void)ws_size;
  const float* x       = (const float*)d_in[0];
  const int*   seq_len = (const int*)d_in[1];
  const float* W       = (const float*)d_in[2];
  const float* bias    = (const float*)d_in[3];
  float* out = (float*)d_out;

  char* ws = (char*)d_ws;
  u16*   xw   = (u16*)(ws);                                  // 128 MB [T][256][64][16] bf16
  u16*   xb   = (u16*)(ws + (size_t)134217728);              // 16 MB  x bf16 [B][T][D]
  u16*   wxt  = (u16*)(ws + (size_t)150994944);              // 4 MB   WxT bf16 [4096][512]
  u16*   whT  = (u16*)(ws + (size_t)155189248);              // 8 MB   W_h fragments [256][16384]
  char*  hreg = ws + (size_t)163577856;                      // 256 KB h dbuf + 256 KB flags
  u16*   hbuf = (u16*)hreg;
  uint32_t* flags = (uint32_t*)(hreg + 262144);              // 256 x 128 B padded slots

  k_init<<<dim3(256), dim3(256), 0, stream>>>((uint64_t*)hreg);          // zero h dbuf + flags
  k_convert_x<<<dim3(8192), dim3(256), 0, stream>>>(x, xb);
  k_transpose_wx<<<dim3(8, 64), dim3(256), 0, stream>>>(W, wxt);
  k_prep_wh<<<dim3(256), dim3(256), 0, stream>>>(W, whT);
  k_gemm_xw<<<dim3(128, 32), dim3(256), 0, stream>>>(xb, wxt, bias, xw);

  {
    void* kargs[] = { (void*)&whT, (void*)&xw, (void*)&seq_len,
                      (void*)&hbuf, (void*)&flags, (void*)&out };
    hipLaunchCooperativeKernel((const void*)k_lstm_persist, dim3(256), dim3(256),
                               kargs, 0, stream);
  }
}

// Round 2
// 2642.604 us; speedup vs baseline: 1.7057x; 1.7057x over previous
//
#include <hip/hip_runtime.h>
#include <stdint.h>

typedef unsigned short u16;
typedef __bf16 bf16_t;
typedef bf16_t bf16x8 __attribute__((ext_vector_type(8)));
typedef float f32x4 __attribute__((ext_vector_type(4)));

#define Bdim 64
#define Tdim 256
#define Ddim 512
#define Hdim 1024
#define NGdim 4096

// ---------- helpers ----------
__device__ __forceinline__ u16 f2bf(float f) {
  union { float f; uint32_t u; } v; v.f = f;
  return (u16)((v.u + 0x7FFFu + ((v.u >> 16) & 1u)) >> 16);   // RNE
}
__device__ __forceinline__ float bf2f(u16 h) {
  union { uint32_t u; float f; } v; v.u = ((uint32_t)h) << 16;
  return v.f;
}
__device__ __forceinline__ float sigm(float x) { return 1.0f / (1.0f + __expf(-x)); }
__device__ __forceinline__ float tanh_fast(float x) { return 2.0f / (1.0f + __expf(-2.0f * x)) - 1.0f; }

__device__ __forceinline__ void load_lds16(const void* g, void* l) {
  __builtin_amdgcn_global_load_lds(
      (const __attribute__((address_space(1))) uint32_t*)g,
      (__attribute__((address_space(3))) uint32_t*)l, 16, 0, 0);
}
__device__ __forceinline__ f32x4 mfma_bf16(bf16x8 a, bf16x8 b, f32x4 c) {
  return __builtin_amdgcn_mfma_f32_16x16x32_bf16(a, b, c, 0, 0, 0);
}

// ---------- kernel 0: zero h double-buffer (bf16) + flags region ----------
__global__ void k_init(uint64_t* __restrict__ zreg) {
  zreg[blockIdx.x * 256 + threadIdx.x] = 0ull;   // 256 WGs x 256 x 8 B = 512 KB
}

// ---------- kernel 1: x fp32 -> bf16 ----------
__global__ void k_convert_x(const float* __restrict__ x, u16* __restrict__ xb) {
  const int i = (blockIdx.x * 256 + threadIdx.x) * 4;
  float4 v = *(const float4*)(x + i);
  union { u16 h[4]; uint2 v2; } p;
  p.h[0] = f2bf(v.x); p.h[1] = f2bf(v.y); p.h[2] = f2bf(v.z); p.h[3] = f2bf(v.w);
  *(uint2*)(xb + i) = p.v2;
}

// ---------- kernel 2: W[0:512][4096] fp32 -> WxT bf16 [4096][512] ----------
__global__ void k_transpose_wx(const float* __restrict__ W, u16* __restrict__ wxt) {
  __shared__ float tile[64][65];
  const int k0 = blockIdx.x * 64;   // 8 blocks
  const int n0 = blockIdx.y * 64;   // 64 blocks
  const int tn = threadIdx.x & 63, tk = threadIdx.x >> 6;
#pragma unroll
  for (int r = 0; r < 16; r++) {
    const int k = r * 4 + tk;
    tile[k][tn] = W[(size_t)(k0 + k) * NGdim + n0 + tn];
  }
  __syncthreads();
  for (int cid = threadIdx.x; cid < 512; cid += 256) {
    const int nl = cid >> 3, kc = cid & 7;
    union { u16 h[8]; uint4 v; } p;
#pragma unroll
    for (int j = 0; j < 8; j++) p.h[j] = f2bf(tile[kc * 8 + j][nl]);
    *(uint4*)(wxt + (size_t)(n0 + nl) * Ddim + k0 + kc * 8) = p.v;
  }
}

// ---------- kernel 3: W_h -> per-WG fragment layout whT[gid][128 kb][16 n][8 kk] bf16 (8 MB) ----------
__global__ void k_prep_wh(const float* __restrict__ W, u16* __restrict__ whT) {
  const int gid = blockIdx.x;          // 0..255
  u16* dst = whT + (size_t)gid * 16384;
  const int gate = threadIdx.x & 3;
  const int kb = threadIdx.x >> 2;     // 0..63
  const int ngc = gate * 1024 + gid * 4;
#pragma unroll 1
  for (int kk = 0; kk < 16; kk++) {
    const int k = kb * 16 + kk;
    const float4 wv = *(const float4*)(W + (size_t)(Ddim + k) * NGdim + ngc);
    const int base = ((k >> 3) * 16 + gate * 4) * 8 + (k & 7);
    dst[base]      = f2bf(wv.x);
    dst[base + 8]  = f2bf(wv.y);
    dst[base + 16] = f2bf(wv.z);
    dst[base + 24] = f2bf(wv.w);
  }
}

// ---------- kernel 4: XW = x @ Wx + b, permuted output [T][256 g][64 b][16 nl] bf16 ----------
__global__ __launch_bounds__(256) void k_gemm_xw(
    const u16* __restrict__ xb, const u16* __restrict__ wxt,
    const float* __restrict__ bias, u16* __restrict__ xw)
{
  __shared__ u16 smem[8192];        // 16 KB: sA [kg][128 m][8], sB [kg][128 j][8]
  const int Mtile = blockIdx.x;     // 0..127 (2 t's x 64 b)
  const int Ntile = blockIdx.y;     // 0..31
  const int g0 = Ntile * 8;
  const int tid = threadIdx.x;
  const int lane = tid & 63;
  const int wave = tid >> 6;
  const int wm = wave & 1, wn = wave >> 1;
  const int t0 = Mtile * 2;

  const size_t a_r0 = ((size_t)lane * Tdim + t0) * Ddim;
  const size_t a_r1 = ((size_t)lane * Tdim + t0 + 1) * Ddim;
  const int jc0 = lane, jc1 = 64 + lane;
  const int ng0 = (jc0 >> 5) * 1024 + (g0 + ((jc0 >> 2) & 7)) * 4 + (jc0 & 3);
  const int ng1 = (jc1 >> 5) * 1024 + (g0 + ((jc1 >> 2) & 7)) * 4 + (jc1 & 3);
  const size_t b_r0 = (size_t)ng0 * Ddim;
  const size_t b_r1 = (size_t)ng1 * Ddim;

  u16* sA = smem;
  u16* sB = smem + 4096;
  char* dA0 = (char*)sA + wave * 2048;
  char* dA1 = dA0 + 1024;
  char* dB0 = (char*)sB + wave * 2048;
  char* dB1 = dB0 + 1024;

  f32x4 zero4 = {0.f, 0.f, 0.f, 0.f};
  f32x4 acc[4][4];
#pragma unroll
  for (int i = 0; i < 4; i++)
#pragma unroll
    for (int j = 0; j < 4; j++) acc[i][j] = zero4;

  const int fa = (((lane >> 4) * 128) + wm * 64 + (lane & 15)) * 16;
  const int fb = (((lane >> 4) * 128) + wn * 64 + (lane & 15)) * 16;

  for (int k0 = 0; k0 < Ddim; k0 += 32) {
    const int koff = k0 + 8 * wave;
    __syncthreads();
    load_lds16(xb + a_r0 + koff, dA0);
    load_lds16(xb + a_r1 + koff, dA1);
    load_lds16(wxt + b_r0 + koff, dB0);
    load_lds16(wxt + b_r1 + koff, dB1);
    __syncthreads();
    bf16x8 af[4], bfr[4];
#pragma unroll
    for (int i = 0; i < 4; i++) {
      af[i]  = *(const bf16x8*)((const char*)sA + fa + i * 256);
      bfr[i] = *(const bf16x8*)((const char*)sB + fb + i * 256);
    }
#pragma unroll
    for (int mt = 0; mt < 4; mt++)
#pragma unroll
      for (int nt = 0; nt < 4; nt++)
        acc[mt][nt] = mfma_bf16(af[mt], bfr[nt], acc[mt][nt]);
  }

#pragma unroll 1
  for (int th = 0; th < 2; th++) {
    __syncthreads();
    if (wm == th) {
      const int q = lane >> 4, col0 = wn * 64 + (lane & 15);
#pragma unroll
      for (int mt = 0; mt < 4; mt++)
#pragma unroll
        for (int nt = 0; nt < 4; nt++)
#pragma unroll
          for (int i = 0; i < 4; i++)
            smem[(mt * 16 + q * 4 + i) * 128 + col0 + nt * 16] = f2bf(acc[mt][nt][i]);
    }
    __syncthreads();
    const int t = t0 + th;
    for (int cid = tid; cid < 512; cid += 256) {
      const int gsub = cid >> 6;
      const int b = cid & 63;
      union { u16 h[16]; uint4 v[2]; } pack;
#pragma unroll
      for (int gate = 0; gate < 4; gate++)
#pragma unroll
        for (int c = 0; c < 4; c++) {
          float v = bf2f(smem[b * 128 + gate * 32 + gsub * 4 + c])
                  + bias[gate * 1024 + (g0 + gsub) * 4 + c];
          pack.h[gate * 4 + c] = f2bf(v);
        }
      uint4* dst = (uint4*)(xw + ((((size_t)t * 256) + g0 + gsub) * 64 + b) * 16);
      dst[0] = pack.v[0];
      dst[1] = pack.v[1];
    }
  }
}

// ---------- kernel 5: persistent cooperative LSTM recurrence (fence-free sync) ----------
// One launch, 256 steps. 256 WGs x 256 threads (1 WG/CU). Per step:
//   producers: write-through agent-scope h stores -> s_waitcnt vmcnt(0) -> relaxed flag store
//   consumers: wave0 polls 256 packed flags (16 cache lines, coalesced) -> __syncthreads
//              -> h read via sc0 sc1 (coherence-point) loads, NO fences / buffer_inv anywhere.
// The R1 version spent ~15 us/step in per-wave acquire fences (buffer_inv of L1+L2 x 1024/step)
// and 128B-padded flag polling; this removes every cache-maintenance op from the loop.
__global__ __launch_bounds__(256, 1) void k_lstm_persist(
    const u16* __restrict__ whT, const u16* __restrict__ xw,
    const int* __restrict__ seq_len, u16* __restrict__ hbuf,
    uint32_t* __restrict__ flags, float* __restrict__ out)
{
  __shared__ float zlds[4 * 64 * 17];   // [wave][batch][col], col-pad 17
  __shared__ u16 hpack[64][4];
  const int gid  = blockIdx.x;          // 0..255
  const int tid  = threadIdx.x;
  const int lane = tid & 63;
  const int wave = tid >> 6;
  const int b_t  = tid >> 2;            // owned batch
  const int c_t  = tid & 3;             // owned h-col within gid*4
  const int q    = lane >> 4;
  const int col  = lane & 15;

  // W_h fragments, loaded once: wave w covers K [w*256, w*256+256)
  bf16x8 bw[8];
  {
    const u16* wp = whT + (size_t)gid * 16384 + ((size_t)q * 16 + col) * 8;
#pragma unroll
    for (int j = 0; j < 8; j++)
      bw[j] = *(const bf16x8*)(wp + (wave * 8 + j) * 512);
  }

  const int slen = seq_len[b_t];
  float c_reg = 0.f, h_reg = 0.f;

  // per-lane A-fragment base: batch = col + mt*16, k = wave*256 + q*8 + j*32
  const u16* pa0 = hbuf + (size_t)col * Hdim + wave * 256 + q * 8;

  for (int t = 0; t < Tdim; t++) {
    u16* hdst = hbuf + (size_t)((t + 1) & 1) * (Bdim * Hdim);

    if (t > 0) {
      if (wave == 0) {
        const uint32_t gen = (uint32_t)t;
        const uint32_t* fp = flags + lane;   // packed 4B stride: 256 flags = 16 lines
        for (;;) {
          const uint32_t f0 = __hip_atomic_load(fp,       __ATOMIC_RELAXED, __HIP_MEMORY_SCOPE_AGENT);
          const uint32_t f1 = __hip_atomic_load(fp + 64,  __ATOMIC_RELAXED, __HIP_MEMORY_SCOPE_AGENT);
          const uint32_t f2 = __hip_atomic_load(fp + 128, __ATOMIC_RELAXED, __HIP_MEMORY_SCOPE_AGENT);
          const uint32_t f3 = __hip_atomic_load(fp + 192, __ATOMIC_RELAXED, __HIP_MEMORY_SCOPE_AGENT);
          if (__all((f0 >= gen) && (f1 >= gen) && (f2 >= gen) && (f3 >= gen))) break;
        }
      }
      __syncthreads();   // no fence: h loads below bypass L1/L2 (sc0 sc1)
    }

    // issue all 32 coherent h loads (LLC-direct), then one wait
    const u16* pa_t = pa0 + (size_t)(t & 1) * (Bdim * Hdim);
    f32x4 av[32];
#pragma unroll
    for (int mt = 0; mt < 4; mt++)
#pragma unroll
      for (int j = 0; j < 8; j++) {
        const u16* ap = pa_t + (size_t)mt * 16 * Hdim + j * 32;
        asm volatile("global_load_dwordx4 %0, %1, off sc0 sc1"
                     : "=v"(av[mt * 8 + j]) : "v"(ap));
      }

    // precomputed x@Wx + b contribution for this (t, b, cols) — normal cached loads
    const u16* xwp = xw + ((((size_t)t * 256) + gid) * 64 + b_t) * 16 + c_t;
    const float xi = bf2f(xwp[0]);
    const float xj = bf2f(xwp[4]);
    const float xf = bf2f(xwp[8]);
    const float xo = bf2f(xwp[12]);

    asm volatile("s_waitcnt vmcnt(0)" ::: "memory");
    __builtin_amdgcn_sched_barrier(0);   // rule #18: keep MFMAs behind the wait

    const f32x4 zero4 = {0.f, 0.f, 0.f, 0.f};
    f32x4 acc[4] = {zero4, zero4, zero4, zero4};
#pragma unroll
    for (int j = 0; j < 8; j++)
#pragma unroll
      for (int mt = 0; mt < 4; mt++)
        acc[mt] = mfma_bf16(__builtin_bit_cast(bf16x8, av[mt * 8 + j]), bw[j], acc[mt]);

    // partial z tile -> LDS (C/D layout: col=lane&15, row=(lane>>4)*4+i)
#pragma unroll
    for (int mt = 0; mt < 4; mt++)
#pragma unroll
      for (int i = 0; i < 4; i++)
        zlds[(wave * 64 + mt * 16 + q * 4 + i) * 17 + col] = acc[mt][i];
    __syncthreads();

    // cross-wave K-reduction + gates; thread owns (b_t, gid*4 + c_t)
    float zi = xi, zj = xj, zf = xf, zo = xo;
#pragma unroll
    for (int w = 0; w < 4; w++) {
      const float* zr = zlds + (w * 64 + b_t) * 17 + c_t;
      zi += zr[0]; zj += zr[4]; zf += zr[8]; zo += zr[12];
    }
    if (t < slen) {
      c_reg = c_reg * sigm(zf + 1.0f) + sigm(zi) * tanh_fast(zj);
      h_reg = tanh_fast(c_reg) * sigm(zo);
    }

    if (t == Tdim - 1) break;   // final h stays in h_reg

    // publish this WG's h slice: write-through agent stores, drain, then flag
    hpack[b_t][c_t] = f2bf(h_reg);
    __syncthreads();
    if (wave == 0) {
      const uint64_t pk = *(const uint64_t*)(&hpack[lane][0]);
      __hip_atomic_store((uint64_t*)(hdst + (size_t)lane * Hdim + gid * 4), pk,
                         __ATOMIC_RELAXED, __HIP_MEMORY_SCOPE_AGENT);
      asm volatile("s_waitcnt vmcnt(0)" ::: "memory");   // h at coherence point
      if (lane == 0)
        __hip_atomic_store(flags + gid, (uint32_t)(t + 1),
                           __ATOMIC_RELAXED, __HIP_MEMORY_SCOPE_AGENT);
    }
  }

  out[(size_t)b_t * Hdim + gid * 4 + c_t] = h_reg;
}

// ---------- host ----------
extern "C" void kernel_launch(void* const* d_in, const int* in_sizes, int n_in,
                              void* d_out, int out_size, void* d_ws, size_t ws_size,
                              hipStream_t stream) {
  (void)in_sizes; (void)n_in; (void)out_size; (void)ws_size;
  const float* x       = (const float*)d_in[0];
  const int*   seq_len = (const int*)d_in[1];
  const float* W       = (const float*)d_in[2];
  const float* bias    = (const float*)d_in[3];
  float* out = (float*)d_out;

  char* ws = (char*)d_ws;
  u16*   xw   = (u16*)(ws);                                  // 128 MB [T][256][64][16] bf16
  u16*   xb   = (u16*)(ws + (size_t)134217728);              // 16 MB  x bf16 [B][T][D]
  u16*   wxt  = (u16*)(ws + (size_t)150994944);              // 4 MB   WxT bf16 [4096][512]
  u16*   whT  = (u16*)(ws + (size_t)155189248);              // 8 MB   W_h fragments [256][16384]
  char*  hreg = ws + (size_t)163577856;                      // 256 KB h dbuf + flags
  u16*   hbuf = (u16*)hreg;
  uint32_t* flags = (uint32_t*)(hreg + 262144);              // 256 x 4 B packed (16 lines)

  k_init<<<dim3(256), dim3(256), 0, stream>>>((uint64_t*)hreg);          // zero h dbuf + flags
  k_convert_x<<<dim3(8192), dim3(256), 0, stream>>>(x, xb);
  k_transpose_wx<<<dim3(8, 64), dim3(256), 0, stream>>>(W, wxt);
  k_prep_wh<<<dim3(256), dim3(256), 0, stream>>>(W, whT);
  k_gemm_xw<<<dim3(128, 32), dim3(256), 0, stream>>>(xb, wxt, bias, xw);

  {
    void* kargs[] = { (void*)&whT, (void*)&xw, (void*)&seq_len,
                      (void*)&hbuf, (void*)&flags, (void*)&out };
    hipLaunchCooperativeKernel((const void*)k_lstm_persist, dim3(256), dim3(256),
                               kargs, 0, stream);
  }
}

// Round 3
// 1602.503 us; speedup vs baseline: 2.8128x; 1.6490x over previous
//
#include <hip/hip_runtime.h>
#include <stdint.h>

typedef unsigned short u16;
typedef __bf16 bf16_t;
typedef bf16_t bf16x8 __attribute__((ext_vector_type(8)));
typedef float f32x4 __attribute__((ext_vector_type(4)));

#define Bdim 64
#define Tdim 256
#define Ddim 512
#define Hdim 1024
#define NGdim 4096

// ---------- helpers ----------
__device__ __forceinline__ u16 f2bf(float f) {
  union { float f; uint32_t u; } v; v.f = f;
  return (u16)((v.u + 0x7FFFu + ((v.u >> 16) & 1u)) >> 16);   // RNE
}
__device__ __forceinline__ float bf2f(u16 h) {
  union { uint32_t u; float f; } v; v.u = ((uint32_t)h) << 16;
  return v.f;
}
__device__ __forceinline__ float sigm(float x) { return 1.0f / (1.0f + __expf(-x)); }
__device__ __forceinline__ float tanh_fast(float x) { return 2.0f / (1.0f + __expf(-2.0f * x)) - 1.0f; }

__device__ __forceinline__ void load_lds16(const void* g, void* l) {
  __builtin_amdgcn_global_load_lds(
      (const __attribute__((address_space(1))) uint32_t*)g,
      (__attribute__((address_space(3))) uint32_t*)l, 16, 0, 0);
}
__device__ __forceinline__ f32x4 mfma_bf16(bf16x8 a, bf16x8 b, f32x4 c) {
  return __builtin_amdgcn_mfma_f32_16x16x32_bf16(a, b, c, 0, 0, 0);
}

// ---------- kernel 0: zero h double-buffer (bf16) + flags region ----------
__global__ void k_init(uint64_t* __restrict__ zreg) {
  zreg[blockIdx.x * 256 + threadIdx.x] = 0ull;   // 256 WGs x 256 x 8 B = 512 KB
}

// ---------- kernel 1: x fp32 -> bf16 ----------
__global__ void k_convert_x(const float* __restrict__ x, u16* __restrict__ xb) {
  const int i = (blockIdx.x * 256 + threadIdx.x) * 4;
  float4 v = *(const float4*)(x + i);
  union { u16 h[4]; uint2 v2; } p;
  p.h[0] = f2bf(v.x); p.h[1] = f2bf(v.y); p.h[2] = f2bf(v.z); p.h[3] = f2bf(v.w);
  *(uint2*)(xb + i) = p.v2;
}

// ---------- kernel 2: W[0:512][4096] fp32 -> WxT bf16 [4096][512] ----------
__global__ void k_transpose_wx(const float* __restrict__ W, u16* __restrict__ wxt) {
  __shared__ float tile[64][65];
  const int k0 = blockIdx.x * 64;   // 8 blocks
  const int n0 = blockIdx.y * 64;   // 64 blocks
  const int tn = threadIdx.x & 63, tk = threadIdx.x >> 6;
#pragma unroll
  for (int r = 0; r < 16; r++) {
    const int k = r * 4 + tk;
    tile[k][tn] = W[(size_t)(k0 + k) * NGdim + n0 + tn];
  }
  __syncthreads();
  for (int cid = threadIdx.x; cid < 512; cid += 256) {
    const int nl = cid >> 3, kc = cid & 7;
    union { u16 h[8]; uint4 v; } p;
#pragma unroll
    for (int j = 0; j < 8; j++) p.h[j] = f2bf(tile[kc * 8 + j][nl]);
    *(uint4*)(wxt + (size_t)(n0 + nl) * Ddim + k0 + kc * 8) = p.v;
  }
}

// ---------- kernel 3: W_h -> per-wg fragment layout whT[wg(64)][kt(32)][gate(4)][q(4)][hc(16)][ki(8)] ----------
// wg owns h-cols [wg*16, wg*16+16). Element (k, gate, hc) = W[(512+k)][gate*1024 + wg*16 + hc].
__global__ void k_prep_wh(const float* __restrict__ W, u16* __restrict__ whT) {
  const int wg = blockIdx.x;           // 0..63
  u16* dst = whT + (size_t)wg * 65536;
  const int gate = threadIdx.x & 3;
  const int hcq  = (threadIdx.x >> 2) & 3;
  const int kb   = threadIdx.x >> 4;   // 0..15
#pragma unroll 1
  for (int kk = 0; kk < 64; kk++) {
    const int k = kb * 64 + kk;
    const float4 wv = *(const float4*)(W + (size_t)(Ddim + k) * NGdim
                                         + gate * 1024 + wg * 16 + hcq * 4);
    const int kt = k >> 5, kl = k & 31, q = kl >> 3, ki = kl & 7;
    const int base = kt * 2048 + gate * 512 + q * 128 + ki;
    dst[base + (hcq * 4 + 0) * 8] = f2bf(wv.x);
    dst[base + (hcq * 4 + 1) * 8] = f2bf(wv.y);
    dst[base + (hcq * 4 + 2) * 8] = f2bf(wv.z);
    dst[base + (hcq * 4 + 3) * 8] = f2bf(wv.w);
  }
}

// ---------- kernel 4: XW = x @ Wx + b, output layout [t][1024 hcol][64 b][4 gates] bf16 ----------
__global__ __launch_bounds__(256) void k_gemm_xw(
    const u16* __restrict__ xb, const u16* __restrict__ wxt,
    const float* __restrict__ bias, u16* __restrict__ xw)
{
  __shared__ u16 smem[8192];        // 16 KB: sA [kg][128 m][8], sB [kg][128 j][8]
  const int Mtile = blockIdx.x;     // 0..127 (2 t's x 64 b)
  const int Ntile = blockIdx.y;     // 0..31
  const int g0 = Ntile * 8;
  const int tid = threadIdx.x;
  const int lane = tid & 63;
  const int wave = tid >> 6;
  const int wm = wave & 1, wn = wave >> 1;
  const int t0 = Mtile * 2;

  const size_t a_r0 = ((size_t)lane * Tdim + t0) * Ddim;
  const size_t a_r1 = ((size_t)lane * Tdim + t0 + 1) * Ddim;
  const int jc0 = lane, jc1 = 64 + lane;
  const int ng0 = (jc0 >> 5) * 1024 + (g0 + ((jc0 >> 2) & 7)) * 4 + (jc0 & 3);
  const int ng1 = (jc1 >> 5) * 1024 + (g0 + ((jc1 >> 2) & 7)) * 4 + (jc1 & 3);
  const size_t b_r0 = (size_t)ng0 * Ddim;
  const size_t b_r1 = (size_t)ng1 * Ddim;

  u16* sA = smem;
  u16* sB = smem + 4096;
  char* dA0 = (char*)sA + wave * 2048;
  char* dA1 = dA0 + 1024;
  char* dB0 = (char*)sB + wave * 2048;
  char* dB1 = dB0 + 1024;

  f32x4 zero4 = {0.f, 0.f, 0.f, 0.f};
  f32x4 acc[4][4];
#pragma unroll
  for (int i = 0; i < 4; i++)
#pragma unroll
    for (int j = 0; j < 4; j++) acc[i][j] = zero4;

  const int fa = (((lane >> 4) * 128) + wm * 64 + (lane & 15)) * 16;
  const int fb = (((lane >> 4) * 128) + wn * 64 + (lane & 15)) * 16;

  for (int k0 = 0; k0 < Ddim; k0 += 32) {
    const int koff = k0 + 8 * wave;
    __syncthreads();
    load_lds16(xb + a_r0 + koff, dA0);
    load_lds16(xb + a_r1 + koff, dA1);
    load_lds16(wxt + b_r0 + koff, dB0);
    load_lds16(wxt + b_r1 + koff, dB1);
    __syncthreads();
    bf16x8 af[4], bfr[4];
#pragma unroll
    for (int i = 0; i < 4; i++) {
      af[i]  = *(const bf16x8*)((const char*)sA + fa + i * 256);
      bfr[i] = *(const bf16x8*)((const char*)sB + fb + i * 256);
    }
#pragma unroll
    for (int mt = 0; mt < 4; mt++)
#pragma unroll
      for (int nt = 0; nt < 4; nt++)
        acc[mt][nt] = mfma_bf16(af[mt], bfr[nt], acc[mt][nt]);
  }

#pragma unroll 1
  for (int th = 0; th < 2; th++) {
    __syncthreads();
    if (wm == th) {
      const int q = lane >> 4, col0 = wn * 64 + (lane & 15);
#pragma unroll
      for (int mt = 0; mt < 4; mt++)
#pragma unroll
        for (int nt = 0; nt < 4; nt++)
#pragma unroll
          for (int i = 0; i < 4; i++)
            smem[(mt * 16 + q * 4 + i) * 128 + col0 + nt * 16] = f2bf(acc[mt][nt][i]);
    }
    __syncthreads();
    const int t = t0 + th;
    for (int cid = tid; cid < 512; cid += 256) {
      const int gsub = cid >> 6;
      const int b = cid & 63;
#pragma unroll
      for (int c = 0; c < 4; c++) {
        union { u16 h[4]; uint2 v; } pk;
#pragma unroll
        for (int gate = 0; gate < 4; gate++) {
          float v = bf2f(smem[b * 128 + gate * 32 + gsub * 4 + c])
                  + bias[gate * 1024 + (g0 + gsub) * 4 + c];
          pk.h[gate] = f2bf(v);
        }
        *(uint2*)(xw + (((size_t)t * 1024 + (g0 + gsub) * 4 + c) * 64 + b) * 4) = pk.v;
      }
    }
  }
}

// ---------- kernel 5: persistent LSTM, batch-partitioned (4 groups x 16 batches) ----------
// 256 WGs: group g_grp = gid>>6 owns batches [g_grp*16, +16); wg = gid&63 owns h-cols
// [wg*16, +16) x 4 gates (64 N-cols, full K=1024). Sync scope = 64 WGs of own group only.
// A-traffic: 32 KB/WG/step (8 MB aggregate, 4x less than R2). M=16 exact MFMA tile.
// Weights stationary in VGPRs: bw[8][4] = 128 VGPRs/lane. Waves split K (4 x 256).
__global__ __launch_bounds__(256, 1) void k_lstm_persist(
    const u16* __restrict__ whT, const u16* __restrict__ xw,
    const int* __restrict__ seq_len, u16* __restrict__ hbuf,
    uint32_t* __restrict__ flags, float* __restrict__ out)
{
  __shared__ float zlds[64 * 66];       // [wave*16+m][66 (pad)]
  __shared__ u16 hpack[16][16];         // [local batch][local hcol]
  const int gid   = blockIdx.x;
  const int g_grp = gid >> 6;           // batch group 0..3
  const int wg    = gid & 63;           // h-col owner within group
  const int tid   = threadIdx.x;
  const int lane  = tid & 63;
  const int wave  = tid >> 6;
  const int q     = lane >> 4;
  const int col   = lane & 15;
  const int b_t   = tid & 15;           // owned local batch
  const int hc_t  = tid >> 4;           // owned local hcol
  const int g16   = g_grp * 16;

  // stationary weights: wave covers K [wave*256, wave*256+256)
  bf16x8 bw[8][4];
  {
    const u16* wp = whT + (size_t)wg * 65536 + (size_t)(q * 16 + col) * 8;
#pragma unroll
    for (int kt = 0; kt < 8; kt++)
#pragma unroll
      for (int g = 0; g < 4; g++)
        bw[kt][g] = *(const bf16x8*)(wp + (wave * 8 + kt) * 2048 + g * 512);
  }

  const int slen = seq_len[g16 + b_t];
  float c_reg = 0.f, h_reg = 0.f;

  // A fragment base: batch row m = col, k = wave*256 + kt*32 + q*8 + j
  const u16* pa0 = hbuf + (size_t)(g16 + col) * Hdim + wave * 256 + q * 8;

  for (int t = 0; t < Tdim; t++) {
    // xw gate prefetch (h-independent): issue before poll so HBM latency hides
    const u16* xwp = xw + (((size_t)t * 1024 + wg * 16 + hc_t) * 64 + g16 + b_t) * 4;
    uint2 xwv;
    asm volatile("global_load_dwordx2 %0, %1, off" : "=v"(xwv) : "v"(xwp));

    if (t > 0) {
      if (wave == 0) {
        const uint32_t gen = (uint32_t)t;
        const uint32_t* fp = flags + g_grp * 64 + lane;   // 64 flags = 4 lines
        uint32_t f;
        do {
          f = __hip_atomic_load(fp, __ATOMIC_RELAXED, __HIP_MEMORY_SCOPE_AGENT);
        } while (!__all(f >= gen));
      }
      __syncthreads();   // no fence: h loads below bypass L1/L2 (sc0 sc1)
    }

    // coherent (LLC-direct) h loads: 8 x 16 B per lane = wave's 16x256 A-slice
    const u16* pa_t = pa0 + (size_t)(t & 1) * (Bdim * Hdim);
    f32x4 av[8];
#pragma unroll
    for (int kt = 0; kt < 8; kt++)
      asm volatile("global_load_dwordx4 %0, %1, off sc0 sc1"
                   : "=v"(av[kt]) : "v"(pa_t + kt * 32));

    asm volatile("s_waitcnt vmcnt(0)" ::: "memory");
    __builtin_amdgcn_sched_barrier(0);   // rule #18: keep MFMAs behind the wait

    const f32x4 zero4 = {0.f, 0.f, 0.f, 0.f};
    f32x4 acc[4] = {zero4, zero4, zero4, zero4};
#pragma unroll
    for (int kt = 0; kt < 8; kt++)
#pragma unroll
      for (int g = 0; g < 4; g++)
        acc[g] = mfma_bf16(__builtin_bit_cast(bf16x8, av[kt]), bw[kt][g], acc[g]);

    // partial z -> LDS (C/D: n = lane&15, m = q*4+i); stride 66 => ~2-way (free)
#pragma unroll
    for (int g = 0; g < 4; g++)
#pragma unroll
      for (int i = 0; i < 4; i++)
        zlds[(wave * 16 + q * 4 + i) * 66 + g * 16 + col] = acc[g][i];
    __syncthreads();

    // cross-wave K-reduction; thread owns (b_t, wg*16 + hc_t)
    float zg[4];
#pragma unroll
    for (int g = 0; g < 4; g++) {
      float s = 0.f;
#pragma unroll
      for (int w = 0; w < 4; w++)
        s += zlds[(w * 16 + b_t) * 66 + g * 16 + hc_t];
      zg[g] = s;
    }
    union { uint2 v; u16 h[4]; } xp; xp.v = xwv;
    const float zi = zg[0] + bf2f(xp.h[0]);
    const float zj = zg[1] + bf2f(xp.h[1]);
    const float zf = zg[2] + bf2f(xp.h[2]);
    const float zo = zg[3] + bf2f(xp.h[3]);
    if (t < slen) {
      c_reg = c_reg * sigm(zf + 1.0f) + sigm(zi) * tanh_fast(zj);
      h_reg = tanh_fast(c_reg) * sigm(zo);
    }

    if (t == Tdim - 1) break;   // final h stays in registers

    // publish h slice (512 B): write-through agent stores, drain, then flag
    hpack[b_t][hc_t] = f2bf(h_reg);
    __syncthreads();
    if (wave == 0) {
      u16* hdst = hbuf + (size_t)((t + 1) & 1) * (Bdim * Hdim);
      const int pb = lane >> 2, ph = (lane & 3) * 4;
      const uint64_t pk = *(const uint64_t*)(&hpack[pb][ph]);
      __hip_atomic_store((uint64_t*)(hdst + (size_t)(g16 + pb) * Hdim + wg * 16 + ph), pk,
                         __ATOMIC_RELAXED, __HIP_MEMORY_SCOPE_AGENT);
      asm volatile("s_waitcnt vmcnt(0)" ::: "memory");   // h at coherence point
      if (lane == 0)
        __hip_atomic_store(flags + gid, (uint32_t)(t + 1),
                           __ATOMIC_RELAXED, __HIP_MEMORY_SCOPE_AGENT);
    }
  }

  out[(size_t)(g16 + b_t) * Hdim + wg * 16 + hc_t] = h_reg;
}

// ---------- host ----------
extern "C" void kernel_launch(void* const* d_in, const int* in_sizes, int n_in,
                              void* d_out, int out_size, void* d_ws, size_t ws_size,
                              hipStream_t stream) {
  (void)in_sizes; (void)n_in; (void)out_size; (void)ws_size;
  const float* x       = (const float*)d_in[0];
  const int*   seq_len = (const int*)d_in[1];
  const float* W       = (const float*)d_in[2];
  const float* bias    = (const float*)d_in[3];
  float* out = (float*)d_out;

  char* ws = (char*)d_ws;
  u16*   xw   = (u16*)(ws);                                  // 128 MB [t][hcol][b][gate] bf16
  u16*   xb   = (u16*)(ws + (size_t)134217728);              // 16 MB  x bf16 [B][T][D]
  u16*   wxt  = (u16*)(ws + (size_t)150994944);              // 4 MB   WxT bf16 [4096][512]
  u16*   whT  = (u16*)(ws + (size_t)155189248);              // 8 MB   W_h fragments [64][65536]
  char*  hreg = ws + (size_t)163577856;                      // 256 KB h dbuf + flags
  u16*   hbuf = (u16*)hreg;
  uint32_t* flags = (uint32_t*)(hreg + 262144);              // 256 x 4 B packed

  k_init<<<dim3(256), dim3(256), 0, stream>>>((uint64_t*)hreg);          // zero h dbuf + flags
  k_convert_x<<<dim3(8192), dim3(256), 0, stream>>>(x, xb);
  k_transpose_wx<<<dim3(8, 64), dim3(256), 0, stream>>>(W, wxt);
  k_prep_wh<<<dim3(64), dim3(256), 0, stream>>>(W, whT);
  k_gemm_xw<<<dim3(128, 32), dim3(256), 0, stream>>>(xb, wxt, bias, xw);

  {
    void* kargs[] = { (void*)&whT, (void*)&xw, (void*)&seq_len,
                      (void*)&hbuf, (void*)&flags, (void*)&out };
    hipLaunchCooperativeKernel((const void*)k_lstm_persist, dim3(256), dim3(256),
                               kargs, 0, stream);
  }
}